// Round 9
// baseline (114.438 us; speedup 1.0000x reference)
//
#include <hip/hip_runtime.h>
#include <math.h>

// Problem constants
#define B_    4
#define T_    2048
#define D_    512
#define H_    4
#define ROWS_ 8192
#define CHSZ_ 128     // timesteps per chunk
#define NCHK_ 16      // chunks per (b,h)

typedef unsigned short ushort_t;
typedef unsigned int   uint_t;
typedef __attribute__((ext_vector_type(8))) __bf16         bfx8;
typedef __attribute__((ext_vector_type(8))) unsigned short u16x8;
typedef __attribute__((ext_vector_type(4))) float          fx4;

__device__ __forceinline__ ushort_t f2bf(float f) {
    union { float f; uint_t u; } v; v.f = f;
    return (ushort_t)((v.u + 0x7FFFu + ((v.u >> 16) & 1u)) >> 16);
}
__device__ __forceinline__ float bf2f(ushort_t u) {
    union { uint_t u; float f; } v; v.u = ((uint_t)u) << 16; return v.f;
}

// ---------------------------------------------------------------------------
// gemm_scanA: projection GEMM (128x64 tile, K=512) + inline fp32 a-decay +
// chunk-local scan. Reads x (fp32) and raw weights directly — no prep/pack
// kernel. Grid: 256 = 64 row-chunks x 4 heads, head in high bits (the 4 head
// blocks of a chunk are 64 apart -> same XCD -> x tile L2-shared).
//
// A-tile: fp32 x staged, converted to bf16 in-register; the same fp32 values
// feed pa[s] = partial dot x·Wa[:,h] (fp32-exact decay path). Each row's dot
// is spread over 8 threads (sc slices); width-8 shuffle butterfly completes
// it after the K-loop; -softplus(z+ba) -> s_a[] in LDS.
// B-tile: head h's 64 cols pulled straight from Wq/Wk/Wv/Wg (s=0: q|k,
// s=1: v|g, col = h*16+(sr&15)), converted to bf16.
// Scan: per-wave-max frame (chunk frame underflows — R4's NaN lesson).
// ---------------------------------------------------------------------------
__global__ __launch_bounds__(256) void gemm_scanA(const float* __restrict__ x,
                                                  const float* __restrict__ Wa,
                                                  const float* __restrict__ ba,
                                                  const float* __restrict__ Wq,
                                                  const float* __restrict__ Wk,
                                                  const float* __restrict__ Wv,
                                                  const float* __restrict__ Wg,
                                                  float* __restrict__ stateWS,
                                                  float* __restrict__ chunkSum,
                                                  ushort_t* __restrict__ gBuf) {
    __shared__ ushort_t As[128 * 72];   // reused as Ct after K-loop
    __shared__ ushort_t Bs[64 * 72];
    __shared__ float s_a[128];
    __shared__ float s_a0;
    __shared__ float s_wmax[2];
    __shared__ float s_tot[17];

    const int rc = blockIdx.x & 63;     // row chunk (b*16 + chunk)
    const int h  = blockIdx.x >> 6;
    const int m0 = rc * 128;
    const int b  = rc >> 4, chunk = rc & 15;
    const int bh = b * 4 + h;

    const int tid = threadIdx.x;
    const int wave = tid >> 6, lane = tid & 63;
    const int fr = lane & 15, quad = lane >> 4;
    const int sr = tid >> 3, sc = (tid & 7) * 8;

    // B-source selection for this thread's two staging rows (n=sr, n=32+sr)
    const int colw = h * 16 + (sr & 15);
    const float* W1 = (sr < 16) ? Wq : Wk;   // Bs rows 0..31  (q|k)
    const float* W2 = (sr < 16) ? Wv : Wg;   // Bs rows 32..63 (v|g)

    fx4 acc[2][4];
    #pragma unroll
    for (int i = 0; i < 2; i++)
        #pragma unroll
        for (int j = 0; j < 4; j++) acc[i][j] = (fx4)0.f;

    float pa[4] = {0.f, 0.f, 0.f, 0.f};   // partial x·Wa[:,h] per row slice

    // prefetch registers
    float4 raF[4][2];
    float  rbF[2][8];
    float  rwa[8];
    #pragma unroll
    for (int s = 0; s < 4; s++) {
        const float* xp = x + (size_t)(m0 + s * 32 + sr) * D_ + sc;
        raF[s][0] = *(const float4*)xp;
        raF[s][1] = *(const float4*)(xp + 4);
    }
    #pragma unroll
    for (int j = 0; j < 8; j++) {
        rbF[0][j] = W1[(size_t)(sc + j) * 64 + colw];
        rbF[1][j] = W2[(size_t)(sc + j) * 64 + colw];
        rwa[j]    = Wa[(size_t)(sc + j) * 4 + h];
    }

    for (int it = 0; it < 8; it++) {
        // commit prefetched tile to LDS (convert fp32 -> bf16) + a partials
        #pragma unroll
        for (int s = 0; s < 4; s++) {
            float xv[8] = {raF[s][0].x, raF[s][0].y, raF[s][0].z, raF[s][0].w,
                           raF[s][1].x, raF[s][1].y, raF[s][1].z, raF[s][1].w};
            u16x8 u;
            #pragma unroll
            for (int j = 0; j < 8; j++) {
                u[j] = f2bf(xv[j]);
                pa[s] = fmaf(xv[j], rwa[j], pa[s]);
            }
            *(u16x8*)&As[(s * 32 + sr) * 72 + sc] = u;
        }
        #pragma unroll
        for (int s = 0; s < 2; s++) {
            u16x8 u;
            #pragma unroll
            for (int j = 0; j < 8; j++) u[j] = f2bf(rbF[s][j]);
            *(u16x8*)&Bs[(s * 32 + sr) * 72 + sc] = u;
        }
        __syncthreads();
        // prefetch next k-slice (latency hides behind MFMA below)
        if (it < 7) {
            const int k0 = (it + 1) * 64;
            #pragma unroll
            for (int s = 0; s < 4; s++) {
                const float* xp = x + (size_t)(m0 + s * 32 + sr) * D_ + k0 + sc;
                raF[s][0] = *(const float4*)xp;
                raF[s][1] = *(const float4*)(xp + 4);
            }
            #pragma unroll
            for (int j = 0; j < 8; j++) {
                rbF[0][j] = W1[(size_t)(k0 + sc + j) * 64 + colw];
                rbF[1][j] = W2[(size_t)(k0 + sc + j) * 64 + colw];
                rwa[j]    = Wa[(size_t)(k0 + sc + j) * 4 + h];
            }
        }
        // compute on the committed tile
        #pragma unroll
        for (int ks = 0; ks < 64; ks += 32) {
            bfx8 af[2], bfr[4];
            #pragma unroll
            for (int mi = 0; mi < 2; mi++)
                af[mi] = *(const bfx8*)&As[(wave * 32 + mi * 16 + fr) * 72 + ks + quad * 8];
            #pragma unroll
            for (int ni = 0; ni < 4; ni++)
                bfr[ni] = *(const bfx8*)&Bs[(ni * 16 + fr) * 72 + ks + quad * 8];
            #pragma unroll
            for (int mi = 0; mi < 2; mi++)
                #pragma unroll
                for (int ni = 0; ni < 4; ni++)
                    acc[mi][ni] = __builtin_amdgcn_mfma_f32_16x16x32_bf16(af[mi], bfr[ni], acc[mi][ni], 0, 0, 0);
        }
        __syncthreads();
    }

    // C-tile (bf16) into As-as-Ct: row_local x 72 stride, cols 0..63
    #pragma unroll
    for (int mi = 0; mi < 2; mi++)
        #pragma unroll
        for (int ni = 0; ni < 4; ni++)
            #pragma unroll
            for (int r = 0; r < 4; r++) {
                int rl = wave * 32 + mi * 16 + quad * 4 + r;
                int cl = ni * 16 + fr;
                As[rl * 72 + cl] = f2bf(acc[mi][ni][r]);
            }

    // finish the a-dots: butterfly over the 8 sc-threads of each row
    #pragma unroll
    for (int s = 0; s < 4; s++) {
        #pragma unroll
        for (int m = 1; m < 8; m <<= 1) pa[s] += __shfl_xor(pa[s], m, 8);
    }
    if ((tid & 7) == 0) {
        const float bah = ba[h];
        #pragma unroll
        for (int s = 0; s < 4; s++) {
            float z = pa[s] + bah;
            s_a[s * 32 + sr] = -(fmaxf(z, 0.f) + log1pf(expf(-fabsf(z))));
        }
    }
    __syncthreads();

    // ---- chunk-local scan: threads 0..127 (waves 0,1), one per row ----
    const bool active = (tid < 128);
    float bid = 0.f, a = 0.f;
    float v[16];
    if (active) {
        const ushort_t* ct = &As[tid * 72];
        u16x8 q0 = *(const u16x8*)(ct +  0), q1 = *(const u16x8*)(ct +  8);
        u16x8 k0 = *(const u16x8*)(ct + 16), k1 = *(const u16x8*)(ct + 24);
        u16x8 v0 = *(const u16x8*)(ct + 32), v1 = *(const u16x8*)(ct + 40);
        #pragma unroll
        for (int j = 0; j < 8; j++) {
            bid = fmaf(bf2f(q0[j]), bf2f(k0[j]), bid);
            bid = fmaf(bf2f(q1[j]), bf2f(k1[j]), bid);
            v[j]     = bf2f(v0[j]);
            v[8 + j] = bf2f(v1[j]);
        }
        bid *= 0.25f;
        a = s_a[tid];
    }

    // cumA inclusive scan over 128 rows (2 waves + LDS bridge)
    float ca = a;
    #pragma unroll
    for (int off = 1; off < 64; off <<= 1) {
        float up = __shfl_up(ca, off);
        if (lane >= off) ca += up;
    }
    if (tid == 63) s_a0 = ca;
    __syncthreads();
    if (active && wave == 1) ca += s_a0;

    float lg = bid - ca;      // chunk-local log-weight (increases with t)

    // per-wave max Mw (frame for this wave's prefix sums)
    float Mw = active ? lg : -1e30f;
    #pragma unroll
    for (int off = 32; off; off >>= 1) Mw = fmaxf(Mw, __shfl_xor(Mw, off));
    if (active && lane == 0) s_wmax[wave] = Mw;
    __syncthreads();
    const float M0 = s_wmax[0], M1 = s_wmax[1];
    const float Mc = fmaxf(M0, M1);

    // plain prefix sums of (d, n[16]) = e^{lg-Mw} * (1, v) within wave
    float d = active ? __expf(lg - Mw) : 0.f;
    float n[16];
    #pragma unroll
    for (int j = 0; j < 16; j++) n[j] = d * v[j];
    #pragma unroll
    for (int off = 1; off < 64; off <<= 1) {
        float ud = __shfl_up(d, off);
        float un[16];
        #pragma unroll
        for (int j = 0; j < 16; j++) un[j] = __shfl_up(n[j], off);
        if (lane >= off) {
            d += ud;
            #pragma unroll
            for (int j = 0; j < 16; j++) n[j] += un[j];
        }
    }
    if (tid == 63) {
        s_tot[0] = d;
        #pragma unroll
        for (int j = 0; j < 16; j++) s_tot[1 + j] = n[j];
    }
    __syncthreads();
    if (active && wave == 1) {
        float al = __expf(M0 - Mc), be = __expf(M1 - Mc);
        d = s_tot[0] * al + d * be;
        #pragma unroll
        for (int j = 0; j < 16; j++) n[j] = s_tot[1 + j] * al + n[j] * be;
    }
    const float myM = (wave == 0) ? M0 : Mc;   // frame of this row's (d,n)

    // ---- write per-row state, g-tile, chunk summary ----
    if (active) {
        const int t = chunk * CHSZ_ + tid;
        const size_t eidx = (size_t)bh * T_ + t;
        stateWS[eidx] = myM;
        stateWS[32768 + eidx] = d;
        #pragma unroll
        for (int j = 0; j < 16; j++) stateWS[(size_t)(2 + j) * 32768 + eidx] = n[j];

        const ushort_t* ct = &As[tid * 72];
        u16x8 g0 = *(const u16x8*)(ct + 48), g1 = *(const u16x8*)(ct + 56);
        *(u16x8*)(gBuf + eidx * 16)     = g0;
        *(u16x8*)(gBuf + eidx * 16 + 8) = g1;

        if (tid == 127) {
            float* cs = chunkSum + (size_t)(bh * NCHK_ + chunk) * 20;
            cs[0] = Mc; cs[1] = d;
            #pragma unroll
            for (int j = 0; j < 16; j++) cs[2 + j] = n[j];
            cs[18] = ca;   // chunk total of a
        }
    }
}

// ---------------------------------------------------------------------------
// scan_gemm: fused look-back + combine + gate + output GEMM.
// Grid (4, 128): block = 64 rows x 128 cols of out, K=64. Wo staged with
// in-register transpose+bf16-convert (WoT buffer eliminated). Wave 0 runs
// the parallel look-back over chunkSum for all 4 heads (lane = h*16+p);
// all 256 threads (head = wave, row = lane) combine their row state with
// the prefix, gate, and write the 64x64 Y-tile into LDS; then MFMA GEMM.
// ---------------------------------------------------------------------------
__global__ __launch_bounds__(256) void scan_gemm(const float* __restrict__ stateWS,
                                                 const float* __restrict__ chunkSum,
                                                 const ushort_t* __restrict__ gBuf,
                                                 const float* __restrict__ bg,
                                                 const float* __restrict__ Wo,
                                                 float* __restrict__ C) {
    __shared__ ushort_t Ys[64 * 72];
    __shared__ ushort_t Bs[128 * 72];
    __shared__ float s_pref[4][18];

    const int m0 = blockIdx.y * 64;     // global row base
    const int n0 = blockIdx.x * 128;    // output column base
    const int b  = m0 >> 11;            // batch
    const int tt = m0 & 2047;           // batch-local t of tile row 0
    const int chunk = tt >> 7;          // containing chunk

    const int tid = threadIdx.x;
    const int wave = tid >> 6, lane = tid & 63;

    // stage Wo^T rows n0..n0+127 (cols of Wo), K=64, transpose+convert
    const int sr = tid >> 3, sc = (tid & 7) * 8;
    #pragma unroll
    for (int s = 0; s < 4; s++) {
        int rr = s * 32 + sr;
        u16x8 u;
        #pragma unroll
        for (int j = 0; j < 8; j++)
            u[j] = f2bf(Wo[(size_t)(sc + j) * D_ + n0 + rr]);
        *(u16x8*)&Bs[rr * 72 + sc] = u;
    }

    // per-(head,row) state loads: head = wave, row = lane (coalesced per plane)
    const int h = wave, r = lane;
    const int bh = b * 4 + h;
    const size_t eidx = (size_t)bh * T_ + tt + r;
    float m_row = stateWS[eidx];
    float d_row = stateWS[32768 + eidx];
    float n_row[16];
    #pragma unroll
    for (int j = 0; j < 16; j++) n_row[j] = stateWS[(size_t)(2 + j) * 32768 + eidx];
    u16x8 g0 = *(const u16x8*)(gBuf + eidx * 16);
    u16x8 g1 = *(const u16x8*)(gBuf + eidx * 16 + 8);

    // wave 0: parallel look-back for all 4 heads (lane = hh*16 + p)
    if (wave == 0) {
        const int hh = lane >> 4, p = lane & 15;
        const int bhh = b * 4 + hh;
        float mf = -1e30f, dd = 0.f, aT = 0.f;
        float nn[16];
        #pragma unroll
        for (int j = 0; j < 16; j++) nn[j] = 0.f;
        if (p < chunk) {
            const float* cs = chunkSum + (size_t)(bhh * NCHK_ + p) * 20;
            mf = cs[0]; dd = cs[1];
            #pragma unroll
            for (int j = 0; j < 16; j++) nn[j] = cs[2 + j];
            aT = cs[18];
        }
        // suffix sums of aTot within the 16-lane head group
        float off = aT;
        #pragma unroll
        for (int s = 1; s < 16; s <<= 1) {
            float t2 = __shfl_down(off, s, 16);
            if (p + s < chunk) off += t2;
        }
        if (p < chunk) mf += off;   // shift into this chunk's local frame
        // tree-combine the 16 lanes of each head group
        #pragma unroll
        for (int s = 1; s < 16; s <<= 1) {
            float m2 = __shfl_xor(mf, s, 16);
            float d2 = __shfl_xor(dd, s, 16);
            float mx = fmaxf(mf, m2);
            float al = __expf(mf - mx), be = __expf(m2 - mx);
            #pragma unroll
            for (int j = 0; j < 16; j++) {
                float n2 = __shfl_xor(nn[j], s, 16);
                nn[j] = nn[j] * al + n2 * be;
            }
            dd = dd * al + d2 * be;
            mf = mx;
        }
        if (p == 0) {
            s_pref[hh][0] = mf; s_pref[hh][1] = dd;
            #pragma unroll
            for (int j = 0; j < 16; j++) s_pref[hh][2 + j] = nn[j];
        }
    }
    __syncthreads();

    // combine prefix with row state, gate, write Y-tile to LDS
    {
        const float M = s_pref[h][0], D = s_pref[h][1];
        const float mx = fmaxf(M, m_row);
        const float al = __expf(M - mx), be = __expf(m_row - mx);
        const float invd = 1.f / (D * al + d_row * be);
        u16x8 o0, o1;
        #pragma unroll
        for (int j = 0; j < 16; j++) {
            float Nj = s_pref[h][2 + j] * al + n_row[j] * be;
            float gpre = ((j < 8) ? bf2f(g0[j]) : bf2f(g1[j - 8])) + bg[h * 16 + j];
            float gate = 1.f / (1.f + __expf(-gpre));
            ushort_t yb = f2bf(Nj * invd * gate);
            if (j < 8) o0[j] = yb; else o1[j - 8] = yb;
        }
        *(u16x8*)&Ys[r * 72 + h * 16]     = o0;
        *(u16x8*)&Ys[r * 72 + h * 16 + 8] = o1;
    }
    __syncthreads();

    // GEMM: out-tile (64 x 128) = Ys (64 x 64) @ Bs(128 x 64)^T
    const int wr = wave >> 1, wc = wave & 1;
    const int fr = lane & 15, quad = lane >> 4;
    fx4 acc[2][4];
    #pragma unroll
    for (int i = 0; i < 2; i++)
        #pragma unroll
        for (int j = 0; j < 4; j++) acc[i][j] = (fx4)0.f;

    #pragma unroll
    for (int ks = 0; ks < 64; ks += 32) {
        bfx8 af[2], bfr[4];
        #pragma unroll
        for (int mi = 0; mi < 2; mi++)
            af[mi] = *(const bfx8*)&Ys[(wr * 32 + mi * 16 + fr) * 72 + ks + quad * 8];
        #pragma unroll
        for (int ni = 0; ni < 4; ni++)
            bfr[ni] = *(const bfx8*)&Bs[(wc * 64 + ni * 16 + fr) * 72 + ks + quad * 8];
        #pragma unroll
        for (int mi = 0; mi < 2; mi++)
            #pragma unroll
            for (int ni = 0; ni < 4; ni++)
                acc[mi][ni] = __builtin_amdgcn_mfma_f32_16x16x32_bf16(af[mi], bfr[ni], acc[mi][ni], 0, 0, 0);
    }

    #pragma unroll
    for (int mi = 0; mi < 2; mi++)
        #pragma unroll
        for (int ni = 0; ni < 4; ni++)
            #pragma unroll
            for (int rr = 0; rr < 4; rr++) {
                int orow = m0 + wr * 32 + mi * 16 + quad * 4 + rr;
                int ocol = n0 + wc * 64 + ni * 16 + fr;
                C[(size_t)orow * D_ + ocol] = acc[mi][ni][rr];
            }
}

// ---------------------------------------------------------------------------
extern "C" void kernel_launch(void* const* d_in, const int* in_sizes, int n_in,
                              void* d_out, int out_size, void* d_ws, size_t ws_size,
                              hipStream_t stream) {
    const float* x  = (const float*)d_in[0];
    const float* Wq = (const float*)d_in[1];
    const float* Wk = (const float*)d_in[2];
    const float* Wv = (const float*)d_in[3];
    const float* Wa = (const float*)d_in[4];
    const float* ba = (const float*)d_in[5];
    const float* Wg = (const float*)d_in[6];
    const float* bg = (const float*)d_in[7];
    const float* Wo = (const float*)d_in[8];
    float* out = (float*)d_out;

    char* w = (char*)d_ws;
    float*    stateWS  = (float*)w;     w += (size_t)18 * 32768 * 4;    // 2.25 MiB
    float*    chunkSum = (float*)w;     w += 256 * 20 * 4;              // 20 KiB
    ushort_t* gBuf     = (ushort_t*)w;  w += (size_t)32768 * 16 * 2;    // 1 MiB

    gemm_scanA<<<256, 256, 0, stream>>>(x, Wa, ba, Wq, Wk, Wv, Wg,
                                        stateWS, chunkSum, gBuf);
    scan_gemm<<<dim3(4, 128), 256, 0, stream>>>(stateWS, chunkSum, gBuf, bg, Wo, out);
}

// Round 10
// 103.562 us; speedup vs baseline: 1.1050x; 1.1050x over previous
//
#include <hip/hip_runtime.h>
#include <math.h>

// Problem constants
#define B_    4
#define T_    2048
#define D_    512
#define H_    4
#define ROWS_ 8192
#define CHSZ_ 128     // timesteps per chunk
#define NCHK_ 16      // chunks per (b,h)

typedef unsigned short ushort_t;
typedef unsigned int   uint_t;
typedef __attribute__((ext_vector_type(8))) __bf16         bfx8;
typedef __attribute__((ext_vector_type(8))) unsigned short u16x8;
typedef __attribute__((ext_vector_type(4))) float          fx4;

__device__ __forceinline__ ushort_t f2bf(float f) {
    union { float f; uint_t u; } v; v.f = f;
    return (ushort_t)((v.u + 0x7FFFu + ((v.u >> 16) & 1u)) >> 16);
}
__device__ __forceinline__ float bf2f(ushort_t u) {
    union { uint_t u; float f; } v; v.u = ((uint_t)u) << 16; return v.f;
}

// ---------------------------------------------------------------------------
// pack_w: weights only (x-path is fused into gemm_scanA — R9 lesson: fuse x,
// keep weight transpose/convert coalesced in a dedicated tiny kernel).
// WcatT2: 256x512 bf16, head-major rows h*64 + {q16|k16|v16|g16}.
// WoT:    512x64 bf16, transposed Wo. Total read: 1.3 MB.
// ---------------------------------------------------------------------------
__global__ __launch_bounds__(256) void pack_w(const float* __restrict__ Wq,
                                              const float* __restrict__ Wk,
                                              const float* __restrict__ Wv,
                                              const float* __restrict__ Wg,
                                              const float* __restrict__ Wo,
                                              ushort_t* __restrict__ WcatT2,
                                              ushort_t* __restrict__ WoT) {
    int idx = blockIdx.x * 256 + threadIdx.x;
    if (idx < 256 * 512) {
        int n = idx >> 9, d = idx & 511;
        int h = n >> 6, r = n & 63, part = r >> 4, j = r & 15;
        int col = h * 16 + j;
        const float* W = (part == 0) ? Wq : (part == 1) ? Wk : (part == 2) ? Wv : Wg;
        WcatT2[idx] = f2bf(W[(size_t)d * 64 + col]);
    } else {
        int r = idx - 256 * 512;          // 0..32767 = n*64 + k
        int n = r >> 6, k = r & 63;
        WoT[r] = f2bf(Wo[(size_t)k * 512 + n]);
    }
}

// ---------------------------------------------------------------------------
// gemm_scanA: projection GEMM (128x64 tile, K=512, register-prefetch) +
// inline fp32 a-decay + chunk-local scan. Reads x directly as fp32 (converted
// to bf16 during LDS commit; same fp32 values feed the exact a-decay dot).
// B staged from WcatT2 with u16x8 vector loads (R7/R8 proven path).
// Wa[:,h] cached in LDS once. Grid: 256 = 64 row-chunks x 4 heads, head in
// high bits (same-chunk heads share an XCD -> x tile L2-shared).
// Scan: per-wave-max frame (chunk frame underflows — R4 NaN lesson).
// ---------------------------------------------------------------------------
__global__ __launch_bounds__(256) void gemm_scanA(const float* __restrict__ x,
                                                  const float* __restrict__ Wa,
                                                  const float* __restrict__ ba,
                                                  const ushort_t* __restrict__ WcatT2,
                                                  float* __restrict__ stateWS,
                                                  float* __restrict__ chunkSum,
                                                  ushort_t* __restrict__ gBuf) {
    __shared__ ushort_t As[128 * 72];   // reused as Ct after K-loop
    __shared__ ushort_t Bs[64 * 72];
    __shared__ float s_wa[512];
    __shared__ float s_a[128];
    __shared__ float s_a0;
    __shared__ float s_wmax[2];
    __shared__ float s_tot[17];

    const int rc = blockIdx.x & 63;     // row chunk (b*16 + chunk)
    const int h  = blockIdx.x >> 6;
    const int m0 = rc * 128;
    const int n0 = h * 64;
    const int b  = rc >> 4, chunk = rc & 15;
    const int bh = b * 4 + h;

    const int tid = threadIdx.x;
    const int wave = tid >> 6, lane = tid & 63;
    const int fr = lane & 15, quad = lane >> 4;
    const int sr = tid >> 3, sc = (tid & 7) * 8;

    // cache Wa[:,h] in LDS (512 floats, once)
    s_wa[tid * 2]     = Wa[(size_t)(tid * 2) * 4 + h];
    s_wa[tid * 2 + 1] = Wa[(size_t)(tid * 2 + 1) * 4 + h];

    fx4 acc[2][4];
    #pragma unroll
    for (int i = 0; i < 2; i++)
        #pragma unroll
        for (int j = 0; j < 4; j++) acc[i][j] = (fx4)0.f;

    float pa[4] = {0.f, 0.f, 0.f, 0.f};   // partial x·Wa[:,h] per row slice

    // prefetch registers
    float4 raF[4][2];
    u16x8  rb[2];
    #pragma unroll
    for (int s = 0; s < 4; s++) {
        const float* xp = x + (size_t)(m0 + s * 32 + sr) * D_ + sc;
        raF[s][0] = *(const float4*)xp;
        raF[s][1] = *(const float4*)(xp + 4);
    }
    #pragma unroll
    for (int s = 0; s < 2; s++)
        rb[s] = *(const u16x8*)(WcatT2 + (size_t)(n0 + s * 32 + sr) * D_ + sc);

    __syncthreads();   // s_wa ready

    for (int it = 0; it < 8; it++) {
        const int kb = it * 64 + sc;
        // commit prefetched tile to LDS (fp32 -> bf16) + a-decay partials
        #pragma unroll
        for (int s = 0; s < 4; s++) {
            float xv[8] = {raF[s][0].x, raF[s][0].y, raF[s][0].z, raF[s][0].w,
                           raF[s][1].x, raF[s][1].y, raF[s][1].z, raF[s][1].w};
            u16x8 u;
            #pragma unroll
            for (int j = 0; j < 8; j++) {
                u[j] = f2bf(xv[j]);
                pa[s] = fmaf(xv[j], s_wa[kb + j], pa[s]);
            }
            *(u16x8*)&As[(s * 32 + sr) * 72 + sc] = u;
        }
        #pragma unroll
        for (int s = 0; s < 2; s++)
            *(u16x8*)&Bs[(s * 32 + sr) * 72 + sc] = rb[s];
        __syncthreads();
        // prefetch next k-slice (latency hides behind MFMA below)
        if (it < 7) {
            const int k0 = (it + 1) * 64;
            #pragma unroll
            for (int s = 0; s < 4; s++) {
                const float* xp = x + (size_t)(m0 + s * 32 + sr) * D_ + k0 + sc;
                raF[s][0] = *(const float4*)xp;
                raF[s][1] = *(const float4*)(xp + 4);
            }
            #pragma unroll
            for (int s = 0; s < 2; s++)
                rb[s] = *(const u16x8*)(WcatT2 + (size_t)(n0 + s * 32 + sr) * D_ + k0 + sc);
        }
        // compute on the committed tile
        #pragma unroll
        for (int ks = 0; ks < 64; ks += 32) {
            bfx8 af[2], bfr[4];
            #pragma unroll
            for (int mi = 0; mi < 2; mi++)
                af[mi] = *(const bfx8*)&As[(wave * 32 + mi * 16 + fr) * 72 + ks + quad * 8];
            #pragma unroll
            for (int ni = 0; ni < 4; ni++)
                bfr[ni] = *(const bfx8*)&Bs[(ni * 16 + fr) * 72 + ks + quad * 8];
            #pragma unroll
            for (int mi = 0; mi < 2; mi++)
                #pragma unroll
                for (int ni = 0; ni < 4; ni++)
                    acc[mi][ni] = __builtin_amdgcn_mfma_f32_16x16x32_bf16(af[mi], bfr[ni], acc[mi][ni], 0, 0, 0);
        }
        __syncthreads();
    }

    // C-tile (bf16) into As-as-Ct: row_local x 72 stride, cols 0..63
    #pragma unroll
    for (int mi = 0; mi < 2; mi++)
        #pragma unroll
        for (int ni = 0; ni < 4; ni++)
            #pragma unroll
            for (int r = 0; r < 4; r++) {
                int rl = wave * 32 + mi * 16 + quad * 4 + r;
                int cl = ni * 16 + fr;
                As[rl * 72 + cl] = f2bf(acc[mi][ni][r]);
            }

    // finish the a-dots: butterfly over the 8 sc-threads of each row
    #pragma unroll
    for (int s = 0; s < 4; s++) {
        #pragma unroll
        for (int m = 1; m < 8; m <<= 1) pa[s] += __shfl_xor(pa[s], m, 8);
    }
    if ((tid & 7) == 0) {
        const float bah = ba[h];
        #pragma unroll
        for (int s = 0; s < 4; s++) {
            float z = pa[s] + bah;
            s_a[s * 32 + sr] = -(fmaxf(z, 0.f) + log1pf(expf(-fabsf(z))));
        }
    }
    __syncthreads();

    // ---- chunk-local scan: threads 0..127 (waves 0,1), one per row ----
    const bool active = (tid < 128);
    float bid = 0.f, a = 0.f;
    float v[16];
    if (active) {
        const ushort_t* ct = &As[tid * 72];
        u16x8 q0 = *(const u16x8*)(ct +  0), q1 = *(const u16x8*)(ct +  8);
        u16x8 k0 = *(const u16x8*)(ct + 16), k1 = *(const u16x8*)(ct + 24);
        u16x8 v0 = *(const u16x8*)(ct + 32), v1 = *(const u16x8*)(ct + 40);
        #pragma unroll
        for (int j = 0; j < 8; j++) {
            bid = fmaf(bf2f(q0[j]), bf2f(k0[j]), bid);
            bid = fmaf(bf2f(q1[j]), bf2f(k1[j]), bid);
            v[j]     = bf2f(v0[j]);
            v[8 + j] = bf2f(v1[j]);
        }
        bid *= 0.25f;
        a = s_a[tid];
    }

    // cumA inclusive scan over 128 rows (2 waves + LDS bridge)
    float ca = a;
    #pragma unroll
    for (int off = 1; off < 64; off <<= 1) {
        float up = __shfl_up(ca, off);
        if (lane >= off) ca += up;
    }
    if (tid == 63) s_a0 = ca;
    __syncthreads();
    if (active && wave == 1) ca += s_a0;

    float lg = bid - ca;      // chunk-local log-weight (increases with t)

    // per-wave max Mw (frame for this wave's prefix sums)
    float Mw = active ? lg : -1e30f;
    #pragma unroll
    for (int off = 32; off; off >>= 1) Mw = fmaxf(Mw, __shfl_xor(Mw, off));
    if (active && lane == 0) s_wmax[wave] = Mw;
    __syncthreads();
    const float M0 = s_wmax[0], M1 = s_wmax[1];
    const float Mc = fmaxf(M0, M1);

    // plain prefix sums of (d, n[16]) = e^{lg-Mw} * (1, v) within wave
    float d = active ? __expf(lg - Mw) : 0.f;
    float n[16];
    #pragma unroll
    for (int j = 0; j < 16; j++) n[j] = d * v[j];
    #pragma unroll
    for (int off = 1; off < 64; off <<= 1) {
        float ud = __shfl_up(d, off);
        float un[16];
        #pragma unroll
        for (int j = 0; j < 16; j++) un[j] = __shfl_up(n[j], off);
        if (lane >= off) {
            d += ud;
            #pragma unroll
            for (int j = 0; j < 16; j++) n[j] += un[j];
        }
    }
    if (tid == 63) {
        s_tot[0] = d;
        #pragma unroll
        for (int j = 0; j < 16; j++) s_tot[1 + j] = n[j];
    }
    __syncthreads();
    if (active && wave == 1) {
        float al = __expf(M0 - Mc), be = __expf(M1 - Mc);
        d = s_tot[0] * al + d * be;
        #pragma unroll
        for (int j = 0; j < 16; j++) n[j] = s_tot[1 + j] * al + n[j] * be;
    }
    const float myM = (wave == 0) ? M0 : Mc;   // frame of this row's (d,n)

    // ---- write per-row state, g-tile, chunk summary ----
    if (active) {
        const int t = chunk * CHSZ_ + tid;
        const size_t eidx = (size_t)bh * T_ + t;
        stateWS[eidx] = myM;
        stateWS[32768 + eidx] = d;
        #pragma unroll
        for (int j = 0; j < 16; j++) stateWS[(size_t)(2 + j) * 32768 + eidx] = n[j];

        const ushort_t* ct = &As[tid * 72];
        u16x8 g0 = *(const u16x8*)(ct + 48), g1 = *(const u16x8*)(ct + 56);
        *(u16x8*)(gBuf + eidx * 16)     = g0;
        *(u16x8*)(gBuf + eidx * 16 + 8) = g1;

        if (tid == 127) {
            float* cs = chunkSum + (size_t)(bh * NCHK_ + chunk) * 20;
            cs[0] = Mc; cs[1] = d;
            #pragma unroll
            for (int j = 0; j < 16; j++) cs[2 + j] = n[j];
            cs[18] = ca;   // chunk total of a
        }
    }
}

// ---------------------------------------------------------------------------
// scan_gemm: fused look-back + combine + gate + output GEMM.
// Grid (4, 128): block = 64 rows x 128 cols of out, K=64. WoT staged with
// u16x8 vector loads. Wave 0 runs the parallel look-back over chunkSum for
// all 4 heads (lane = h*16+p); all 256 threads (head = wave, row = lane)
// combine their row state with the prefix, gate, write the 64x64 Y-tile
// into LDS; then MFMA GEMM.
// ---------------------------------------------------------------------------
__global__ __launch_bounds__(256) void scan_gemm(const float* __restrict__ stateWS,
                                                 const float* __restrict__ chunkSum,
                                                 const ushort_t* __restrict__ gBuf,
                                                 const float* __restrict__ bg,
                                                 const ushort_t* __restrict__ WoT,
                                                 float* __restrict__ C) {
    __shared__ ushort_t Ys[64 * 72];
    __shared__ ushort_t Bs[128 * 72];
    __shared__ float s_pref[4][18];

    const int m0 = blockIdx.y * 64;     // global row base
    const int n0 = blockIdx.x * 128;    // output column base
    const int b  = m0 >> 11;            // batch
    const int tt = m0 & 2047;           // batch-local t of tile row 0
    const int chunk = tt >> 7;          // containing chunk

    const int tid = threadIdx.x;
    const int wave = tid >> 6, lane = tid & 63;

    // stage WoT rows n0..n0+127 (cols of Wo), K=64 — vector loads
    const int sr = tid >> 3, sc = (tid & 7) * 8;
    #pragma unroll
    for (int s = 0; s < 4; s++) {
        int rr = s * 32 + sr;
        *(u16x8*)&Bs[rr * 72 + sc] = *(const u16x8*)(WoT + (size_t)(n0 + rr) * 64 + sc);
    }

    // per-(head,row) state loads: head = wave, row = lane (coalesced per plane)
    const int h = wave, r = lane;
    const int bh = b * 4 + h;
    const size_t eidx = (size_t)bh * T_ + tt + r;
    float m_row = stateWS[eidx];
    float d_row = stateWS[32768 + eidx];
    float n_row[16];
    #pragma unroll
    for (int j = 0; j < 16; j++) n_row[j] = stateWS[(size_t)(2 + j) * 32768 + eidx];
    u16x8 g0 = *(const u16x8*)(gBuf + eidx * 16);
    u16x8 g1 = *(const u16x8*)(gBuf + eidx * 16 + 8);

    // wave 0: parallel look-back for all 4 heads (lane = hh*16 + p)
    if (wave == 0) {
        const int hh = lane >> 4, p = lane & 15;
        const int bhh = b * 4 + hh;
        float mf = -1e30f, dd = 0.f, aT = 0.f;
        float nn[16];
        #pragma unroll
        for (int j = 0; j < 16; j++) nn[j] = 0.f;
        if (p < chunk) {
            const float* cs = chunkSum + (size_t)(bhh * NCHK_ + p) * 20;
            mf = cs[0]; dd = cs[1];
            #pragma unroll
            for (int j = 0; j < 16; j++) nn[j] = cs[2 + j];
            aT = cs[18];
        }
        // suffix sums of aTot within the 16-lane head group
        float off = aT;
        #pragma unroll
        for (int s = 1; s < 16; s <<= 1) {
            float t2 = __shfl_down(off, s, 16);
            if (p + s < chunk) off += t2;
        }
        if (p < chunk) mf += off;   // shift into this chunk's local frame
        // tree-combine the 16 lanes of each head group
        #pragma unroll
        for (int s = 1; s < 16; s <<= 1) {
            float m2 = __shfl_xor(mf, s, 16);
            float d2 = __shfl_xor(dd, s, 16);
            float mx = fmaxf(mf, m2);
            float al = __expf(mf - mx), be = __expf(m2 - mx);
            #pragma unroll
            for (int j = 0; j < 16; j++) {
                float n2 = __shfl_xor(nn[j], s, 16);
                nn[j] = nn[j] * al + n2 * be;
            }
            dd = dd * al + d2 * be;
            mf = mx;
        }
        if (p == 0) {
            s_pref[hh][0] = mf; s_pref[hh][1] = dd;
            #pragma unroll
            for (int j = 0; j < 16; j++) s_pref[hh][2 + j] = nn[j];
        }
    }
    __syncthreads();

    // combine prefix with row state, gate, write Y-tile to LDS
    {
        const float M = s_pref[h][0], D = s_pref[h][1];
        const float mx = fmaxf(M, m_row);
        const float al = __expf(M - mx), be = __expf(m_row - mx);
        const float invd = 1.f / (D * al + d_row * be);
        u16x8 o0, o1;
        #pragma unroll
        for (int j = 0; j < 16; j++) {
            float Nj = s_pref[h][2 + j] * al + n_row[j] * be;
            float gpre = ((j < 8) ? bf2f(g0[j]) : bf2f(g1[j - 8])) + bg[h * 16 + j];
            float gate = 1.f / (1.f + __expf(-gpre));
            ushort_t yb = f2bf(Nj * invd * gate);
            if (j < 8) o0[j] = yb; else o1[j - 8] = yb;
        }
        *(u16x8*)&Ys[r * 72 + h * 16]     = o0;
        *(u16x8*)&Ys[r * 72 + h * 16 + 8] = o1;
    }
    __syncthreads();

    // GEMM: out-tile (64 x 128) = Ys (64 x 64) @ Bs(128 x 64)^T
    const int wr = wave >> 1, wc = wave & 1;
    const int fr = lane & 15, quad = lane >> 4;
    fx4 acc[2][4];
    #pragma unroll
    for (int i = 0; i < 2; i++)
        #pragma unroll
        for (int j = 0; j < 4; j++) acc[i][j] = (fx4)0.f;

    #pragma unroll
    for (int ks = 0; ks < 64; ks += 32) {
        bfx8 af[2], bfr[4];
        #pragma unroll
        for (int mi = 0; mi < 2; mi++)
            af[mi] = *(const bfx8*)&Ys[(wr * 32 + mi * 16 + fr) * 72 + ks + quad * 8];
        #pragma unroll
        for (int ni = 0; ni < 4; ni++)
            bfr[ni] = *(const bfx8*)&Bs[(wc * 64 + ni * 16 + fr) * 72 + ks + quad * 8];
        #pragma unroll
        for (int mi = 0; mi < 2; mi++)
            #pragma unroll
            for (int ni = 0; ni < 4; ni++)
                acc[mi][ni] = __builtin_amdgcn_mfma_f32_16x16x32_bf16(af[mi], bfr[ni], acc[mi][ni], 0, 0, 0);
    }

    #pragma unroll
    for (int mi = 0; mi < 2; mi++)
        #pragma unroll
        for (int ni = 0; ni < 4; ni++)
            #pragma unroll
            for (int rr = 0; rr < 4; rr++) {
                int orow = m0 + wr * 32 + mi * 16 + quad * 4 + rr;
                int ocol = n0 + wc * 64 + ni * 16 + fr;
                C[(size_t)orow * D_ + ocol] = acc[mi][ni][rr];
            }
}

// ---------------------------------------------------------------------------
extern "C" void kernel_launch(void* const* d_in, const int* in_sizes, int n_in,
                              void* d_out, int out_size, void* d_ws, size_t ws_size,
                              hipStream_t stream) {
    const float* x  = (const float*)d_in[0];
    const float* Wq = (const float*)d_in[1];
    const float* Wk = (const float*)d_in[2];
    const float* Wv = (const float*)d_in[3];
    const float* Wa = (const float*)d_in[4];
    const float* ba = (const float*)d_in[5];
    const float* Wg = (const float*)d_in[6];
    const float* bg = (const float*)d_in[7];
    const float* Wo = (const float*)d_in[8];
    float* out = (float*)d_out;

    char* w = (char*)d_ws;
    ushort_t* WcatT2   = (ushort_t*)w;  w += 256 * 512 * 2;             // 256 KiB
    ushort_t* WoT      = (ushort_t*)w;  w += 512 * 64 * 2;              // 64 KiB
    float*    stateWS  = (float*)w;     w += (size_t)18 * 32768 * 4;    // 2.25 MiB
    float*    chunkSum = (float*)w;     w += 256 * 20 * 4;              // 20 KiB
    ushort_t* gBuf     = (ushort_t*)w;  w += (size_t)32768 * 16 * 2;    // 1 MiB

    pack_w<<<640, 256, 0, stream>>>(Wq, Wk, Wv, Wg, Wo, WcatT2, WoT);
    gemm_scanA<<<256, 256, 0, stream>>>(x, Wa, ba, WcatT2,
                                        stateWS, chunkSum, gBuf);
    scan_gemm<<<dim3(4, 128), 256, 0, stream>>>(stateWS, chunkSum, gBuf, bg, WoT, out);
}

// Round 11
// 100.156 us; speedup vs baseline: 1.1426x; 1.0340x over previous
//
#include <hip/hip_runtime.h>
#include <math.h>

// Problem constants
#define B_    4
#define T_    2048
#define D_    512
#define H_    4
#define ROWS_ 8192
#define CHSZ_ 64      // timesteps per chunk (single-wave scan)
#define NCHK_ 32      // chunks per (b,h)

typedef unsigned short ushort_t;
typedef unsigned int   uint_t;
typedef __attribute__((ext_vector_type(8))) __bf16         bfx8;
typedef __attribute__((ext_vector_type(8))) unsigned short u16x8;
typedef __attribute__((ext_vector_type(4))) float          fx4;

__device__ __forceinline__ ushort_t f2bf(float f) {
    union { float f; uint_t u; } v; v.f = f;
    return (ushort_t)((v.u + 0x7FFFu + ((v.u >> 16) & 1u)) >> 16);
}
__device__ __forceinline__ float bf2f(ushort_t u) {
    union { uint_t u; float f; } v; v.u = ((uint_t)u) << 16; return v.f;
}

// ---------------------------------------------------------------------------
// pack_w: weights only (coalesced transpose/convert — R9 lesson).
// WcatT2: 256x512 bf16, head-major rows h*64 + {q16|k16|v16|g16}.
// WoT:    512x64 bf16, transposed Wo.
// ---------------------------------------------------------------------------
__global__ __launch_bounds__(256) void pack_w(const float* __restrict__ Wq,
                                              const float* __restrict__ Wk,
                                              const float* __restrict__ Wv,
                                              const float* __restrict__ Wg,
                                              const float* __restrict__ Wo,
                                              ushort_t* __restrict__ WcatT2,
                                              ushort_t* __restrict__ WoT) {
    int idx = blockIdx.x * 256 + threadIdx.x;
    if (idx < 256 * 512) {
        int n = idx >> 9, d = idx & 511;
        int h = n >> 6, r = n & 63, part = r >> 4, j = r & 15;
        int col = h * 16 + j;
        const float* W = (part == 0) ? Wq : (part == 1) ? Wk : (part == 2) ? Wv : Wg;
        WcatT2[idx] = f2bf(W[(size_t)d * 64 + col]);
    } else {
        int r = idx - 256 * 512;          // 0..32767 = n*64 + k
        int n = r >> 6, k = r & 63;
        WoT[r] = f2bf(Wo[(size_t)k * 512 + n]);
    }
}

// ---------------------------------------------------------------------------
// gemm_scanA: projection GEMM (64x64 tile, K=512, register-prefetch) +
// inline fp32 a-decay + single-wave chunk scan. Grid: 512 = 128 row-chunks
// x 4 heads (head in high bits) -> 2 blocks/CU (vs 1 at CHSZ=128): 2
// waves/SIMD of latency hiding. 64-row chunks make the scan a single wave:
// no cross-wave bridge, one max frame Mc (spread ~45 << 87, no underflow).
// x read directly as fp32 (bf16-converted during LDS commit; same fp32
// values feed the exact a-decay dot). B staged from WcatT2 u16x8-vectorized.
// ---------------------------------------------------------------------------
__global__ __launch_bounds__(256) void gemm_scanA(const float* __restrict__ x,
                                                  const float* __restrict__ Wa,
                                                  const float* __restrict__ ba,
                                                  const ushort_t* __restrict__ WcatT2,
                                                  float* __restrict__ stateWS,
                                                  float* __restrict__ chunkSum,
                                                  ushort_t* __restrict__ gBuf) {
    __shared__ ushort_t As[64 * 72];    // reused as Ct after K-loop
    __shared__ ushort_t Bs[64 * 72];
    __shared__ float s_wa[512];
    __shared__ float s_a[64];

    const int rc = blockIdx.x & 127;    // row chunk (b*32 + chunk)
    const int h  = blockIdx.x >> 7;
    const int m0 = rc * 64;
    const int n0 = h * 64;
    const int b  = rc >> 5, chunk = rc & 31;
    const int bh = b * 4 + h;

    const int tid = threadIdx.x;
    const int wave = tid >> 6, lane = tid & 63;
    const int fr = lane & 15, quad = lane >> 4;
    const int sr = tid >> 3, sc = (tid & 7) * 8;   // sr 0..31

    // cache Wa[:,h] in LDS (512 floats, once)
    s_wa[tid * 2]     = Wa[(size_t)(tid * 2) * 4 + h];
    s_wa[tid * 2 + 1] = Wa[(size_t)(tid * 2 + 1) * 4 + h];

    fx4 acc[4];
    #pragma unroll
    for (int j = 0; j < 4; j++) acc[j] = (fx4)0.f;

    float pa[2] = {0.f, 0.f};   // partial x·Wa[:,h] per staged row

    // prefetch registers
    float4 raF[2][2];
    u16x8  rb[2];
    #pragma unroll
    for (int s = 0; s < 2; s++) {
        const float* xp = x + (size_t)(m0 + s * 32 + sr) * D_ + sc;
        raF[s][0] = *(const float4*)xp;
        raF[s][1] = *(const float4*)(xp + 4);
        rb[s] = *(const u16x8*)(WcatT2 + (size_t)(n0 + s * 32 + sr) * D_ + sc);
    }

    __syncthreads();   // s_wa ready

    for (int it = 0; it < 8; it++) {
        const int kb = it * 64 + sc;
        // commit prefetched tile to LDS (fp32 -> bf16) + a-decay partials
        #pragma unroll
        for (int s = 0; s < 2; s++) {
            float xv[8] = {raF[s][0].x, raF[s][0].y, raF[s][0].z, raF[s][0].w,
                           raF[s][1].x, raF[s][1].y, raF[s][1].z, raF[s][1].w};
            u16x8 u;
            #pragma unroll
            for (int j = 0; j < 8; j++) {
                u[j] = f2bf(xv[j]);
                pa[s] = fmaf(xv[j], s_wa[kb + j], pa[s]);
            }
            *(u16x8*)&As[(s * 32 + sr) * 72 + sc] = u;
            *(u16x8*)&Bs[(s * 32 + sr) * 72 + sc] = rb[s];
        }
        __syncthreads();
        // prefetch next k-slice (latency hides behind MFMA below)
        if (it < 7) {
            const int k0 = (it + 1) * 64;
            #pragma unroll
            for (int s = 0; s < 2; s++) {
                const float* xp = x + (size_t)(m0 + s * 32 + sr) * D_ + k0 + sc;
                raF[s][0] = *(const float4*)xp;
                raF[s][1] = *(const float4*)(xp + 4);
                rb[s] = *(const u16x8*)(WcatT2 + (size_t)(n0 + s * 32 + sr) * D_ + k0 + sc);
            }
        }
        // compute: wave w covers rows w*16..w*16+15 (4 MFMAs per ks step)
        #pragma unroll
        for (int ks = 0; ks < 64; ks += 32) {
            bfx8 af = *(const bfx8*)&As[(wave * 16 + fr) * 72 + ks + quad * 8];
            #pragma unroll
            for (int ni = 0; ni < 4; ni++) {
                bfx8 bfr = *(const bfx8*)&Bs[(ni * 16 + fr) * 72 + ks + quad * 8];
                acc[ni] = __builtin_amdgcn_mfma_f32_16x16x32_bf16(af, bfr, acc[ni], 0, 0, 0);
            }
        }
        __syncthreads();
    }

    // C-tile (bf16) into As-as-Ct: row_local x 72 stride, cols 0..63
    #pragma unroll
    for (int ni = 0; ni < 4; ni++)
        #pragma unroll
        for (int r = 0; r < 4; r++) {
            int rl = wave * 16 + quad * 4 + r;
            int cl = ni * 16 + fr;
            As[rl * 72 + cl] = f2bf(acc[ni][r]);
        }

    // finish the a-dots: butterfly over the 8 sc-threads of each row
    #pragma unroll
    for (int s = 0; s < 2; s++) {
        #pragma unroll
        for (int m = 1; m < 8; m <<= 1) pa[s] += __shfl_xor(pa[s], m, 8);
    }
    if ((tid & 7) == 0) {
        const float bah = ba[h];
        #pragma unroll
        for (int s = 0; s < 2; s++) {
            float z = pa[s] + bah;
            s_a[s * 32 + sr] = -(fmaxf(z, 0.f) + log1pf(expf(-fabsf(z))));
        }
    }
    __syncthreads();

    // ---- chunk scan: wave 0 only (64 rows, single wave, one frame Mc) ----
    if (wave == 0) {
        const ushort_t* ct = &As[lane * 72];
        u16x8 q0 = *(const u16x8*)(ct +  0), q1 = *(const u16x8*)(ct +  8);
        u16x8 k0 = *(const u16x8*)(ct + 16), k1 = *(const u16x8*)(ct + 24);
        u16x8 v0 = *(const u16x8*)(ct + 32), v1 = *(const u16x8*)(ct + 40);
        float bid = 0.f;
        float v[16];
        #pragma unroll
        for (int j = 0; j < 8; j++) {
            bid = fmaf(bf2f(q0[j]), bf2f(k0[j]), bid);
            bid = fmaf(bf2f(q1[j]), bf2f(k1[j]), bid);
            v[j]     = bf2f(v0[j]);
            v[8 + j] = bf2f(v1[j]);
        }
        bid *= 0.25f;
        float a = s_a[lane];

        // cumA inclusive scan (64 lanes)
        float ca = a;
        #pragma unroll
        for (int off = 1; off < 64; off <<= 1) {
            float up = __shfl_up(ca, off);
            if (lane >= off) ca += up;
        }

        float lg = bid - ca;      // chunk-local log-weight

        // chunk max Mc (frame; spread over 64 rows ~45 << 87)
        float Mc = lg;
        #pragma unroll
        for (int off = 32; off; off >>= 1) Mc = fmaxf(Mc, __shfl_xor(Mc, off));

        // plain prefix sums of (d, n[16]) = e^{lg-Mc} * (1, v)
        float d = __expf(lg - Mc);
        float n[16];
        #pragma unroll
        for (int j = 0; j < 16; j++) n[j] = d * v[j];
        #pragma unroll
        for (int off = 1; off < 64; off <<= 1) {
            float ud = __shfl_up(d, off);
            float un[16];
            #pragma unroll
            for (int j = 0; j < 16; j++) un[j] = __shfl_up(n[j], off);
            if (lane >= off) {
                d += ud;
                #pragma unroll
                for (int j = 0; j < 16; j++) n[j] += un[j];
            }
        }

        // write per-row state (frame Mc), g-tile, chunk summary
        const int t = chunk * CHSZ_ + lane;
        const size_t eidx = (size_t)bh * T_ + t;
        stateWS[eidx] = Mc;
        stateWS[32768 + eidx] = d;
        #pragma unroll
        for (int j = 0; j < 16; j++) stateWS[(size_t)(2 + j) * 32768 + eidx] = n[j];

        u16x8 g0 = *(const u16x8*)(ct + 48), g1 = *(const u16x8*)(ct + 56);
        *(u16x8*)(gBuf + eidx * 16)     = g0;
        *(u16x8*)(gBuf + eidx * 16 + 8) = g1;

        if (lane == 63) {
            float* cs = chunkSum + (size_t)(bh * NCHK_ + chunk) * 20;
            cs[0] = Mc; cs[1] = d;
            #pragma unroll
            for (int j = 0; j < 16; j++) cs[2 + j] = n[j];
            cs[18] = ca;   // chunk total of a
        }
    }
}

// ---------------------------------------------------------------------------
// scan_gemm: fused look-back + combine + gate + output GEMM.
// Grid (4, 128): block = 64 rows (one chunk) x 128 cols of out, K=64.
// Look-back: waves 0,1; 32-lane group per head (hh = wave*2 + (lane>>5),
// p = lane&31) over <=31 predecessor chunk summaries: suffix-sum the aTot
// offsets, shift frames, width-32 tree-combine. All 256 threads (head =
// wave, row = lane) then combine their row state with the prefix, gate, and
// write the 64x64 Y-tile into LDS; then MFMA GEMM vs WoT.
// ---------------------------------------------------------------------------
__global__ __launch_bounds__(256) void scan_gemm(const float* __restrict__ stateWS,
                                                 const float* __restrict__ chunkSum,
                                                 const ushort_t* __restrict__ gBuf,
                                                 const float* __restrict__ bg,
                                                 const ushort_t* __restrict__ WoT,
                                                 float* __restrict__ C) {
    __shared__ ushort_t Ys[64 * 72];
    __shared__ ushort_t Bs[128 * 72];
    __shared__ float s_pref[4][18];

    const int m0 = blockIdx.y * 64;     // global row base
    const int n0 = blockIdx.x * 128;    // output column base
    const int b  = m0 >> 11;            // batch
    const int tt = m0 & 2047;           // batch-local t of tile row 0
    const int chunk = tt >> 6;          // containing chunk (0..31)

    const int tid = threadIdx.x;
    const int wave = tid >> 6, lane = tid & 63;

    // stage WoT rows n0..n0+127 (cols of Wo), K=64 — vector loads
    const int sr = tid >> 3, sc = (tid & 7) * 8;
    #pragma unroll
    for (int s = 0; s < 4; s++) {
        int rr = s * 32 + sr;
        *(u16x8*)&Bs[rr * 72 + sc] = *(const u16x8*)(WoT + (size_t)(n0 + rr) * 64 + sc);
    }

    // per-(head,row) state loads: head = wave, row = lane (coalesced per plane)
    const int h = wave, r = lane;
    const int bh = b * 4 + h;
    const size_t eidx = (size_t)bh * T_ + tt + r;
    float m_row = stateWS[eidx];
    float d_row = stateWS[32768 + eidx];
    float n_row[16];
    #pragma unroll
    for (int j = 0; j < 16; j++) n_row[j] = stateWS[(size_t)(2 + j) * 32768 + eidx];
    u16x8 g0 = *(const u16x8*)(gBuf + eidx * 16);
    u16x8 g1 = *(const u16x8*)(gBuf + eidx * 16 + 8);

    // waves 0,1: parallel look-back, 32-lane group per head
    if (wave < 2) {
        const int hh = wave * 2 + (lane >> 5), p = lane & 31;
        const int bhh = b * 4 + hh;
        float mf = -1e30f, dd = 0.f, aT = 0.f;
        float nn[16];
        #pragma unroll
        for (int j = 0; j < 16; j++) nn[j] = 0.f;
        if (p < chunk) {
            const float* cs = chunkSum + (size_t)(bhh * NCHK_ + p) * 20;
            mf = cs[0]; dd = cs[1];
            #pragma unroll
            for (int j = 0; j < 16; j++) nn[j] = cs[2 + j];
            aT = cs[18];
        }
        // suffix sums of aTot within the 32-lane head group
        float off = aT;
        #pragma unroll
        for (int s = 1; s < 32; s <<= 1) {
            float t2 = __shfl_down(off, s, 32);
            if (p + s < chunk) off += t2;
        }
        if (p < chunk) mf += off;   // shift into this chunk's local frame
        // tree-combine the 32 lanes of each head group
        #pragma unroll
        for (int s = 1; s < 32; s <<= 1) {
            float m2 = __shfl_xor(mf, s, 32);
            float d2 = __shfl_xor(dd, s, 32);
            float mx = fmaxf(mf, m2);
            float al = __expf(mf - mx), be = __expf(m2 - mx);
            #pragma unroll
            for (int j = 0; j < 16; j++) {
                float n2 = __shfl_xor(nn[j], s, 32);
                nn[j] = nn[j] * al + n2 * be;
            }
            dd = dd * al + d2 * be;
            mf = mx;
        }
        if (p == 0) {
            s_pref[hh][0] = mf; s_pref[hh][1] = dd;
            #pragma unroll
            for (int j = 0; j < 16; j++) s_pref[hh][2 + j] = nn[j];
        }
    }
    __syncthreads();

    // combine prefix with row state, gate, write Y-tile to LDS
    {
        const float M = s_pref[h][0], D = s_pref[h][1];
        const float mx = fmaxf(M, m_row);
        const float al = __expf(M - mx), be = __expf(m_row - mx);
        const float invd = 1.f / (D * al + d_row * be);
        u16x8 o0, o1;
        #pragma unroll
        for (int j = 0; j < 16; j++) {
            float Nj = s_pref[h][2 + j] * al + n_row[j] * be;
            float gpre = ((j < 8) ? bf2f(g0[j]) : bf2f(g1[j - 8])) + bg[h * 16 + j];
            float gate = 1.f / (1.f + __expf(-gpre));
            ushort_t yb = f2bf(Nj * invd * gate);
            if (j < 8) o0[j] = yb; else o1[j - 8] = yb;
        }
        *(u16x8*)&Ys[r * 72 + h * 16]     = o0;
        *(u16x8*)&Ys[r * 72 + h * 16 + 8] = o1;
    }
    __syncthreads();

    // GEMM: out-tile (64 x 128) = Ys (64 x 64) @ Bs(128 x 64)^T
    const int wr = wave >> 1, wc = wave & 1;
    const int fr = lane & 15, quad = lane >> 4;
    fx4 acc[2][4];
    #pragma unroll
    for (int i = 0; i < 2; i++)
        #pragma unroll
        for (int j = 0; j < 4; j++) acc[i][j] = (fx4)0.f;

    #pragma unroll
    for (int ks = 0; ks < 64; ks += 32) {
        bfx8 af[2], bfr[4];
        #pragma unroll
        for (int mi = 0; mi < 2; mi++)
            af[mi] = *(const bfx8*)&Ys[(wr * 32 + mi * 16 + fr) * 72 + ks + quad * 8];
        #pragma unroll
        for (int ni = 0; ni < 4; ni++)
            bfr[ni] = *(const bfx8*)&Bs[(wc * 64 + ni * 16 + fr) * 72 + ks + quad * 8];
        #pragma unroll
        for (int mi = 0; mi < 2; mi++)
            #pragma unroll
            for (int ni = 0; ni < 4; ni++)
                acc[mi][ni] = __builtin_amdgcn_mfma_f32_16x16x32_bf16(af[mi], bfr[ni], acc[mi][ni], 0, 0, 0);
    }

    #pragma unroll
    for (int mi = 0; mi < 2; mi++)
        #pragma unroll
        for (int ni = 0; ni < 4; ni++)
            #pragma unroll
            for (int rr = 0; rr < 4; rr++) {
                int orow = m0 + wr * 32 + mi * 16 + quad * 4 + rr;
                int ocol = n0 + wc * 64 + ni * 16 + fr;
                C[(size_t)orow * D_ + ocol] = acc[mi][ni][rr];
            }
}

// ---------------------------------------------------------------------------
extern "C" void kernel_launch(void* const* d_in, const int* in_sizes, int n_in,
                              void* d_out, int out_size, void* d_ws, size_t ws_size,
                              hipStream_t stream) {
    const float* x  = (const float*)d_in[0];
    const float* Wq = (const float*)d_in[1];
    const float* Wk = (const float*)d_in[2];
    const float* Wv = (const float*)d_in[3];
    const float* Wa = (const float*)d_in[4];
    const float* ba = (const float*)d_in[5];
    const float* Wg = (const float*)d_in[6];
    const float* bg = (const float*)d_in[7];
    const float* Wo = (const float*)d_in[8];
    float* out = (float*)d_out;

    char* w = (char*)d_ws;
    ushort_t* WcatT2   = (ushort_t*)w;  w += 256 * 512 * 2;             // 256 KiB
    ushort_t* WoT      = (ushort_t*)w;  w += 512 * 64 * 2;              // 64 KiB
    float*    stateWS  = (float*)w;     w += (size_t)18 * 32768 * 4;    // 2.25 MiB
    float*    chunkSum = (float*)w;     w += 512 * 20 * 4;              // 40 KiB
    ushort_t* gBuf     = (ushort_t*)w;  w += (size_t)32768 * 16 * 2;    // 1 MiB

    pack_w<<<640, 256, 0, stream>>>(Wq, Wk, Wv, Wg, Wo, WcatT2, WoT);
    gemm_scanA<<<512, 256, 0, stream>>>(x, Wa, ba, WcatT2,
                                        stateWS, chunkSum, gBuf);
    scan_gemm<<<dim3(4, 128), 256, 0, stream>>>(stateWS, chunkSum, gBuf, bg, WoT, out);
}